// Round 1
// baseline (20.041 us; speedup 1.0000x reference)
//
#include <hip/hip_runtime.h>

namespace {
constexpr int kN = 16384;  // data points
constexpr int kD = 1024;   // features
constexpr int kS = 256;    // samples
constexpr int kRowsPerWave = 2;
constexpr int kWavesPerBlock = 4;
constexpr int kRowsPerBlock = kRowsPerWave * kWavesPerBlock;  // 8
}  // namespace

// One wave (64 lanes) owns one row of X at a time.
// Lane l, chunk k reads float4 at column (k*64+l)*4 -> each instruction is a
// contiguous 1 KiB coalesced segment. w_mu / exp(w_log_var) fragments are
// preloaded into registers once per wave (L1-resident data), reused across
// kRowsPerWave rows. 64-lane shuffle tree reduction for the two dot products.
// Epilogue: lane l owns samples [4l, 4l+4): float4 stores for Y and act.
__global__ __launch_bounds__(256) void mf_mlr_kernel(
    const float* __restrict__ X,
    const float* __restrict__ z,
    const float* __restrict__ w_mu,
    const float* __restrict__ w_lv,
    float* __restrict__ out) {
    const int lane = threadIdx.x & 63;
    const int wave = threadIdx.x >> 6;

    // Per-lane fragments of w_mu and exp(w_log_var): columns (k*64+lane)*4 ..+3
    float4 wm[4], ev[4];
#pragma unroll
    for (int k = 0; k < 4; ++k) {
        const int c = (k * 64 + lane) * 4;
        wm[k] = *reinterpret_cast<const float4*>(w_mu + c);
        const float4 lv = *reinterpret_cast<const float4*>(w_lv + c);
        ev[k] = make_float4(__expf(lv.x), __expf(lv.y), __expf(lv.z), __expf(lv.w));
    }
    const float4 zz = *reinterpret_cast<const float4*>(z + lane * 4);

    const int row0 = (blockIdx.x * kWavesPerBlock + wave) * kRowsPerWave;

#pragma unroll
    for (int r = 0; r < kRowsPerWave; ++r) {
        const int row = row0 + r;
        const float* xr = X + (size_t)row * kD;

        float sm = 0.f, sv = 0.f;
#pragma unroll
        for (int k = 0; k < 4; ++k) {
            const float4 x = *reinterpret_cast<const float4*>(xr + (k * 64 + lane) * 4);
            sm = fmaf(x.x, wm[k].x, sm);
            sm = fmaf(x.y, wm[k].y, sm);
            sm = fmaf(x.z, wm[k].z, sm);
            sm = fmaf(x.w, wm[k].w, sm);
            sv = fmaf(x.x * x.x, ev[k].x, sv);
            sv = fmaf(x.y * x.y, ev[k].y, sv);
            sv = fmaf(x.z * x.z, ev[k].z, sv);
            sv = fmaf(x.w * x.w, ev[k].w, sv);
        }

        // 64-lane butterfly reduction (wave = 64 on CDNA, not 32).
#pragma unroll
        for (int off = 32; off; off >>= 1) {
            sm += __shfl_xor(sm, off, 64);
            sv += __shfl_xor(sv, off, 64);
        }
        const float mean = sm;
        const float stdv = sqrtf(sv);

        float4 a, y;
        a.x = fmaf(stdv, zz.x, mean);
        a.y = fmaf(stdv, zz.y, mean);
        a.z = fmaf(stdv, zz.z, mean);
        a.w = fmaf(stdv, zz.w, mean);
        // Saturates cleanly: __expf(+130)=inf -> y=0; __expf(-130)=0 -> y=1.
        y.x = 1.f / (1.f + __expf(-a.x));
        y.y = 1.f / (1.f + __expf(-a.y));
        y.z = 1.f / (1.f + __expf(-a.z));
        y.w = 1.f / (1.f + __expf(-a.w));

        const size_t ob = (size_t)row * kS + (size_t)lane * 4;
        *reinterpret_cast<float4*>(out + ob) = y;                        // Y
        *reinterpret_cast<float4*>(out + (size_t)kN * kS + ob) = a;      // activation_mat
    }
}

extern "C" void kernel_launch(void* const* d_in, const int* in_sizes, int n_in,
                              void* d_out, int out_size, void* d_ws, size_t ws_size,
                              hipStream_t stream) {
    const float* X    = (const float*)d_in[0];
    const float* z    = (const float*)d_in[1];
    const float* w_mu = (const float*)d_in[2];
    const float* w_lv = (const float*)d_in[3];
    float* out = (float*)d_out;

    dim3 grid(kN / kRowsPerBlock);        // 2048 blocks
    dim3 block(kWavesPerBlock * 64);      // 256 threads
    hipLaunchKernelGGL(mf_mlr_kernel, grid, block, 0, stream,
                       X, z, w_mu, w_lv, out);
}